// Round 6
// baseline (959.968 us; speedup 1.0000x reference)
//
#include <hip/hip_runtime.h>
#include <math.h>

#define BB 512
#define TT 1024
#define LL 48
#define DD 32          // ring depth (slots)

__device__ __forceinline__ float readlane_f(float v, int lane) {
    return __int_as_float(__builtin_amdgcn_readlane(__float_as_int(v), lane));
}

__device__ __forceinline__ void lds_fence() {
    asm volatile("s_waitcnt lgkmcnt(0)" ::: "memory");
}
__device__ __forceinline__ void nap() {
    asm volatile("s_sleep 1");
}

// Full tournament argmax (epilogue only), first-max tie-break.
__device__ __forceinline__ void argmax48(const float* s, float& bestv, int& besti) {
    float val[24];
    int   idx[24];
#pragma unroll
    for (int k = 0; k < 24; ++k) {
        bool c = s[2 * k + 1] > s[2 * k];
        val[k] = c ? s[2 * k + 1] : s[2 * k];
        idx[k] = c ? 2 * k + 1 : 2 * k;
    }
#pragma unroll
    for (int k = 0; k < 12; ++k) {
        bool c = val[2 * k + 1] > val[2 * k];
        val[k] = c ? val[2 * k + 1] : val[2 * k];
        idx[k] = c ? idx[2 * k + 1] : idx[2 * k];
    }
#pragma unroll
    for (int k = 0; k < 6; ++k) {
        bool c = val[2 * k + 1] > val[2 * k];
        val[k] = c ? val[2 * k + 1] : val[2 * k];
        idx[k] = c ? idx[2 * k + 1] : idx[2 * k];
    }
#pragma unroll
    for (int k = 0; k < 3; ++k) {
        bool c = val[2 * k + 1] > val[2 * k];
        val[k] = c ? val[2 * k + 1] : val[2 * k];
        idx[k] = c ? idx[2 * k + 1] : idx[2 * k];
    }
    bool c01 = val[1] > val[0];
    float bv = c01 ? val[1] : val[0];
    int   bi = c01 ? idx[1] : idx[0];
    bool c2 = val[2] > bv;
    bestv = c2 ? val[2] : bv;
    besti = c2 ? idx[2] : bi;
}

__global__ __launch_bounds__(128) void viterbi_kernel(
    const float* __restrict__ emissions,   // [B,T,L]
    const float* __restrict__ transitions, // [L,L]
    const float* __restrict__ start_tr,    // [L]
    const float* __restrict__ end_tr,      // [L]
    int* __restrict__ out)                 // [B,T] int32
{
    __shared__ unsigned char bp[(TT - 1) * LL];       // 49,104 B
    __shared__ __align__(16) float vring[DD][LL];     // 6,144 B: v_{t-1} rows
    __shared__ __align__(16) float bring[DD][LL];     // 6,144 B: best_t rows
    __shared__ int a_cnt, b_cnt, tag_word;

    const int b   = blockIdx.x;
    const int tid = threadIdx.x;
    const int w   = tid >> 6;              // 0 = producer A, 1 = consumer B
    const int j   = tid & 63;
    const int jc  = (j < LL) ? j : (LL - 1);

    if (tid == 0) { a_cnt = 0; b_cnt = 0; }
    __syncthreads();   // one-time init barrier only

    volatile int* pa = &a_cnt;
    volatile int* pb = &b_cnt;

    // Both waves hold transition column jc: tc[i] = trans[i][jc]
    float tc[LL];
#pragma unroll
    for (int i = 0; i < LL; ++i)
        tc[i] = transitions[i * LL + jc];

    int* ob = out + (size_t)b * TT;

    if (w == 0) {
        // ---------------- Wave A: serial value chain (no argmax) ----------------
        const float* em = emissions + (size_t)b * TT * LL;
        float v = start_tr[jc] + em[jc];
        float e1 = em[1 * LL + jc];
        float e2 = em[2 * LL + jc];

#pragma unroll 2
        for (int t = 1; t < TT; ++t) {
            if ((t & 7) == 1) {                     // ring guard, every 8 steps
                while (*pb < t - 25) nap();
            }
            int tn = t + 2; if (tn >= TT) tn = TT - 1;
            float e3 = em[(size_t)tn * LL + jc];    // prefetch 2 iters ahead

            const int slot = t & (DD - 1);
            *(volatile float*)&vring[slot][jc] = v; // publish v_{t-1}

            float s[LL];
#pragma unroll
            for (int i = 0; i < LL; ++i)
                s[i] = readlane_f(v, i) + tc[i];

            // max3 value tree: 48 -> 16 -> 6 -> 2 -> 1  (24 instrs, no idx)
            float m1[16];
#pragma unroll
            for (int k = 0; k < 16; ++k)
                m1[k] = fmaxf(fmaxf(s[3 * k], s[3 * k + 1]), s[3 * k + 2]);
            float m2[6];
#pragma unroll
            for (int k = 0; k < 5; ++k)
                m2[k] = fmaxf(fmaxf(m1[3 * k], m1[3 * k + 1]), m1[3 * k + 2]);
            m2[5] = m1[15];
            float m3a = fmaxf(fmaxf(m2[0], m2[1]), m2[2]);
            float m3b = fmaxf(fmaxf(m2[3], m2[4]), m2[5]);
            float best = fmaxf(m3a, m3b);

            *(volatile float*)&bring[slot][jc] = best;  // publish best_t
            lds_fence();                                // data visible before flag
            if (j == 0) *pa = t;

            v = best + e1;
            e1 = e2; e2 = e3;
        }

        // Epilogue: final tag from v_final (A only)
        v += end_tr[jc];
        float sf[LL];
#pragma unroll
        for (int i = 0; i < LL; ++i)
            sf[i] = readlane_f(v, i);
        float bestv; int tag;
        argmax48(sf, bestv, tag);
        if (j == 0) {
            ob[TT - 1] = tag;
            *(volatile int*)&tag_word = tag;
        }
        lds_fence();
        if (j == 0) *pa = TT;   // done sentinel
    } else {
        // ---------------- Wave B: bp recovery (throughput, no serial chain) ----------------
        for (int t = 1; t < TT; ++t) {
            while (*pa < t) nap();
            lds_fence();   // compiler + hw barrier: ring reads stay below the spin

            const int slot = t & (DD - 1);
            const float4* vp = (const float4*)&vring[slot][0];
            float vb[LL];
#pragma unroll
            for (int k = 0; k < 12; ++k) {          // broadcast reads, conflict-free
                float4 q = vp[k];
                vb[4 * k + 0] = q.x; vb[4 * k + 1] = q.y;
                vb[4 * k + 2] = q.z; vb[4 * k + 3] = q.w;
            }
            float best = bring[slot][jc];           // per-lane read

            float s[LL];
#pragma unroll
            for (int i = 0; i < LL; ++i)
                s[i] = vb[i] + tc[i];               // bitwise == A's s[i]

            // first i with s[i]==best: 4 independent 12-deep chains + min
            int i0 = 63, i1 = 63, i2 = 63, i3 = 63;
#pragma unroll
            for (int k = 11; k >= 0; --k) {
                if (s[k]      == best) i0 = k;
                if (s[12 + k] == best) i1 = 12 + k;
                if (s[24 + k] == best) i2 = 24 + k;
                if (s[36 + k] == best) i3 = 36 + k;
            }
            int arg = min(min(i0, i1), min(i2, i3));

            bp[(t - 1) * LL + jc] = (unsigned char)arg;

            if (((t & 7) == 0) && j == 0) *pb = t;  // consumption progress
        }

        // Backtrack (B wrote all of bp; it is B's own data)
        while (*pa < TT) nap();
        lds_fence();
        int tag = *(volatile int*)&tag_word;

        for (int hi = TT - 2; hi >= 0; hi -= 32) {
            int lo = hi - 31; if (lo < 0) lo = 0;
            int n = hi - lo + 1;

            unsigned int row[32];
#pragma unroll
            for (int k = 0; k < 32; ++k)
                row[k] = (unsigned int)bp[(lo + k) * LL + jc];

            int outv = 0;
#pragma unroll
            for (int k = 31; k >= 0; --k) {
                if (k < n) {
                    tag = __builtin_amdgcn_readlane((int)row[k], tag);
                    outv = (j == k) ? tag : outv;   // tag is SGPR -> one cndmask
                }
            }
            if (j < n) ob[lo + j] = outv;
        }
    }
}

extern "C" void kernel_launch(void* const* d_in, const int* in_sizes, int n_in,
                              void* d_out, int out_size, void* d_ws, size_t ws_size,
                              hipStream_t stream) {
    const float* emissions   = (const float*)d_in[0];
    // d_in[1] = mask — unused by the reference decode body
    const float* transitions = (const float*)d_in[2];
    const float* start_tr    = (const float*)d_in[3];
    const float* end_tr      = (const float*)d_in[4];
    int* out = (int*)d_out;

    viterbi_kernel<<<dim3(BB), dim3(128), 0, stream>>>(
        emissions, transitions, start_tr, end_tr, out);
}

// Round 8
// 674.188 us; speedup vs baseline: 1.4239x; 1.4239x over previous
//
#include <hip/hip_runtime.h>
#include <math.h>

#define BB 512
#define TT 1024
#define LL 48
#define RD 64          // ring depth (slots), = 2 chunks
#define CH 32          // handoff chunk (steps per flag update)

__device__ __forceinline__ float readlane_f(float v, int lane) {
    return __int_as_float(__builtin_amdgcn_readlane(__float_as_int(v), lane));
}

__device__ __forceinline__ void lds_fence() {
    asm volatile("s_waitcnt lgkmcnt(0)" ::: "memory");
}
__device__ __forceinline__ void nap() {
    asm volatile("s_sleep 1");
}

// Full tournament argmax (epilogue only), first-max tie-break.
__device__ __forceinline__ void argmax48(const float* s, float& bestv, int& besti) {
    float val[24];
    int   idx[24];
#pragma unroll
    for (int k = 0; k < 24; ++k) {
        bool c = s[2 * k + 1] > s[2 * k];
        val[k] = c ? s[2 * k + 1] : s[2 * k];
        idx[k] = c ? 2 * k + 1 : 2 * k;
    }
#pragma unroll
    for (int k = 0; k < 12; ++k) {
        bool c = val[2 * k + 1] > val[2 * k];
        val[k] = c ? val[2 * k + 1] : val[2 * k];
        idx[k] = c ? idx[2 * k + 1] : idx[2 * k];
    }
#pragma unroll
    for (int k = 0; k < 6; ++k) {
        bool c = val[2 * k + 1] > val[2 * k];
        val[k] = c ? val[2 * k + 1] : val[2 * k];
        idx[k] = c ? idx[2 * k + 1] : idx[2 * k];
    }
#pragma unroll
    for (int k = 0; k < 3; ++k) {
        bool c = val[2 * k + 1] > val[2 * k];
        val[k] = c ? val[2 * k + 1] : val[2 * k];
        idx[k] = c ? idx[2 * k + 1] : idx[2 * k];
    }
    bool c01 = val[1] > val[0];
    float bv = c01 ? val[1] : val[0];
    int   bi = c01 ? idx[1] : idx[0];
    bool c2 = val[2] > bv;
    bestv = c2 ? val[2] : bv;
    besti = c2 ? idx[2] : bi;
}

__global__ __launch_bounds__(128) void viterbi_kernel(
    const float* __restrict__ emissions,   // [B,T,L]
    const float* __restrict__ transitions, // [L,L]
    const float* __restrict__ start_tr,    // [L]
    const float* __restrict__ end_tr,      // [L]
    int* __restrict__ out)                 // [B,T] int32
{
    __shared__ unsigned char bp[(TT - 1) * LL];       // 49,104 B
    __shared__ __align__(16) float vring[RD][LL];     // 12,288 B: v_{t-1} rows
    __shared__ __align__(16) float bring[RD][LL];     // 12,288 B: best_t rows
    __shared__ int a_cnt, b_cnt, tag_word;

    const int b   = blockIdx.x;
    const int tid = threadIdx.x;
    const int w   = tid >> 6;              // 0 = producer A, 1 = consumer B
    const int j   = tid & 63;
    const int jc  = (j < LL) ? j : (LL - 1);

    if (tid == 0) { a_cnt = 0; b_cnt = 0; }
    __syncthreads();   // one-time init barrier only

    volatile int* pa = &a_cnt;
    volatile int* pb = &b_cnt;

    // Both waves hold transition column jc: tc[i] = trans[i][jc]
    float tc[LL];
#pragma unroll
    for (int i = 0; i < LL; ++i)
        tc[i] = transitions[i * LL + jc];

    int* ob = out + (size_t)b * TT;

    if (w == 0) {
        // ------------- Wave A: serial value chain, chunked publication -------------
        const float* em = emissions + (size_t)b * TT * LL;
        float v = start_tr[jc] + em[jc];
        float e1 = em[1 * LL + jc];
        float e2 = em[2 * LL + jc];

#pragma unroll 2
        for (int t = 1; t < TT; ++t) {
            if ((t & (CH - 1)) == 1) {              // ring-space guard, once/chunk
                while (*pb < t - CH - 1) nap();     // B must be <=2 chunks behind
            }
            int tn = t + 2; if (tn >= TT) tn = TT - 1;
            float e3 = em[(size_t)tn * LL + jc];    // prefetch 2 iters ahead

            const int slot = t & (RD - 1);
            vring[slot][jc] = v;                    // plain store: v_{t-1}

            float s[LL];
#pragma unroll
            for (int i = 0; i < LL; ++i)
                s[i] = readlane_f(v, i) + tc[i];

            // value-only max tree: 48 -> 16 -> 6 -> 2 -> 1 (max3 ops)
            float m1[16];
#pragma unroll
            for (int k = 0; k < 16; ++k)
                m1[k] = fmaxf(fmaxf(s[3 * k], s[3 * k + 1]), s[3 * k + 2]);
            float m2[6];
#pragma unroll
            for (int k = 0; k < 5; ++k)
                m2[k] = fmaxf(fmaxf(m1[3 * k], m1[3 * k + 1]), m1[3 * k + 2]);
            m2[5] = m1[15];
            float best = fmaxf(fmaxf(fmaxf(m2[0], m2[1]), m2[2]),
                               fmaxf(fmaxf(m2[3], m2[4]), m2[5]));

            bring[slot][jc] = best;                 // plain store: best_t

            if ((t & (CH - 1)) == 0) {              // once per chunk: fence + flag
                lds_fence();
                if (j == 0) *pa = t;
            }

            v = best + e1;
            e1 = e2; e2 = e3;
        }

        // Epilogue: final tag
        v += end_tr[jc];
        float sf[LL];
#pragma unroll
        for (int i = 0; i < LL; ++i)
            sf[i] = readlane_f(v, i);
        float bestv; int tag;
        argmax48(sf, bestv, tag);
        if (j == 0) {
            ob[TT - 1] = tag;
            *(volatile int*)&tag_word = tag;
        }
        lds_fence();
        if (j == 0) *pa = TT;   // sentinel: covers last partial chunk + tag
    } else {
        // ------------- Wave B: bp recovery per chunk (throughput, no chain) -------------
        for (int c = 0; c < (TT + CH - 2) / CH; ++c) {
            int lo = 1 + CH * c;
            int hi = lo + CH; if (hi > TT) hi = TT;
            while (*pa < hi - 1) nap();
            lds_fence();   // ring reads stay below the spin; data completed

            for (int t = lo; t < hi; ++t) {
                const int slot = t & (RD - 1);
                const float4* vp = (const float4*)&vring[slot][0];
                float best = bring[slot][jc];       // per-lane b32

                float s[LL];
#pragma unroll
                for (int k = 0; k < 12; ++k) {      // broadcast b128, conflict-free
                    float4 q = vp[k];
                    s[4 * k + 0] = q.x + tc[4 * k + 0];
                    s[4 * k + 1] = q.y + tc[4 * k + 1];
                    s[4 * k + 2] = q.z + tc[4 * k + 2];
                    s[4 * k + 3] = q.w + tc[4 * k + 3];
                }

                // first i with s[i]==best (bitwise-identical adds => exact match)
                int i0 = 63, i1 = 63, i2 = 63, i3 = 63;
#pragma unroll
                for (int k = 11; k >= 0; --k) {
                    if (s[k]      == best) i0 = k;
                    if (s[12 + k] == best) i1 = 12 + k;
                    if (s[24 + k] == best) i2 = 24 + k;
                    if (s[36 + k] == best) i3 = 36 + k;
                }
                int arg = min(min(i0, i1), min(i2, i3));

                bp[(t - 1) * LL + jc] = (unsigned char)arg;
            }

            lds_fence();                 // ring reads done before freeing slots
            if (j == 0) *pb = hi - 1;
        }

        // Backtrack (B wrote all of bp)
        while (*pa < TT) nap();
        lds_fence();
        int tag = *(volatile int*)&tag_word;

        for (int hi = TT - 2; hi >= 0; hi -= 32) {
            int lo = hi - 31; if (lo < 0) lo = 0;
            int n = hi - lo + 1;

            unsigned int row[32];
#pragma unroll
            for (int k = 0; k < 32; ++k)
                row[k] = (unsigned int)bp[(lo + k) * LL + jc];

            int outv = 0;
#pragma unroll
            for (int k = 31; k >= 0; --k) {
                if (k < n) {
                    tag = __builtin_amdgcn_readlane((int)row[k], tag);
                    outv = (j == k) ? tag : outv;   // tag is SGPR -> one cndmask
                }
            }
            if (j < n) ob[lo + j] = outv;
        }
    }
}

extern "C" void kernel_launch(void* const* d_in, const int* in_sizes, int n_in,
                              void* d_out, int out_size, void* d_ws, size_t ws_size,
                              hipStream_t stream) {
    const float* emissions   = (const float*)d_in[0];
    // d_in[1] = mask — unused by the reference decode body
    const float* transitions = (const float*)d_in[2];
    const float* start_tr    = (const float*)d_in[3];
    const float* end_tr      = (const float*)d_in[4];
    int* out = (int*)d_out;

    viterbi_kernel<<<dim3(BB), dim3(128), 0, stream>>>(
        emissions, transitions, start_tr, end_tr, out);
}

// Round 9
// 628.297 us; speedup vs baseline: 1.5279x; 1.0730x over previous
//
#include <hip/hip_runtime.h>
#include <math.h>

#define BB 512
#define TT 1024
#define LL 48

__device__ __forceinline__ float readlane_f(float v, int lane) {
    return __int_as_float(__builtin_amdgcn_readlane(__float_as_int(v), lane));
}

// Tournament argmax over s[0..47], first-max tie-break (epilogue only).
__device__ __forceinline__ void argmax48(const float* s, float& bestv, int& besti) {
    float val[24];
    int   idx[24];
#pragma unroll
    for (int k = 0; k < 24; ++k) {
        bool c = s[2 * k + 1] > s[2 * k];
        val[k] = c ? s[2 * k + 1] : s[2 * k];
        idx[k] = c ? 2 * k + 1 : 2 * k;
    }
#pragma unroll
    for (int k = 0; k < 12; ++k) {
        bool c = val[2 * k + 1] > val[2 * k];
        val[k] = c ? val[2 * k + 1] : val[2 * k];
        idx[k] = c ? idx[2 * k + 1] : idx[2 * k];
    }
#pragma unroll
    for (int k = 0; k < 6; ++k) {
        bool c = val[2 * k + 1] > val[2 * k];
        val[k] = c ? val[2 * k + 1] : val[2 * k];
        idx[k] = c ? idx[2 * k + 1] : idx[2 * k];
    }
#pragma unroll
    for (int k = 0; k < 3; ++k) {
        bool c = val[2 * k + 1] > val[2 * k];
        val[k] = c ? val[2 * k + 1] : val[2 * k];
        idx[k] = c ? idx[2 * k + 1] : idx[2 * k];
    }
    bool c01 = val[1] > val[0];
    float bv = c01 ? val[1] : val[0];
    int   bi = c01 ? idx[1] : idx[0];
    bool c2 = val[2] > bv;
    bestv = c2 ? val[2] : bv;
    besti = c2 ? idx[2] : bi;
}

__global__ __launch_bounds__(64) void viterbi_kernel(
    const float* __restrict__ emissions,   // [B,T,L]
    const float* __restrict__ transitions, // [L,L]
    const float* __restrict__ start_tr,    // [L]
    const float* __restrict__ end_tr,      // [L]
    int* __restrict__ out)                 // [B,T] int32
{
    __shared__ unsigned char bp[(TT - 1) * LL];   // 49,104 B backpointers
    __shared__ __align__(16) float vbuf[64];      // v broadcast buffer (1 row)

    const int b  = blockIdx.x;
    const int j  = threadIdx.x;
    const int jc = (j < LL) ? j : (LL - 1);       // lanes 48-63 mirror lane 47

    // Transition column jc in registers: tc[i] = transitions[i][jc]
    float tc[LL];
#pragma unroll
    for (int i = 0; i < LL; ++i)
        tc[i] = transitions[i * LL + jc];

    const float* em = emissions + (size_t)b * TT * LL;

    float v = start_tr[jc] + em[jc];

    // 3-deep emission pipeline (two loads always in flight)
    float e1 = em[1 * LL + jc];
    float e2 = em[2 * LL + jc];

#pragma unroll 3
    for (int t = 1; t < TT; ++t) {
        int tn = t + 2; if (tn >= TT) tn = TT - 1;
        float e3 = em[(size_t)tn * LL + jc];      // prefetch 2 iters ahead

        // --- broadcast v via LDS (replaces 48 readlanes) ---
        vbuf[j] = v;                              // 64 distinct addrs: conflict-free
        // compiler orders write->read via lgkmcnt (same wave, same array)
        float s[LL];
        const float4* vp = (const float4*)vbuf;
#pragma unroll
        for (int k = 0; k < 12; ++k) {            // same-addr b128 broadcast: free
            float4 q = vp[k];
            s[4 * k + 0] = q.x + tc[4 * k + 0];
            s[4 * k + 1] = q.y + tc[4 * k + 1];
            s[4 * k + 2] = q.z + tc[4 * k + 2];
            s[4 * k + 3] = q.w + tc[4 * k + 3];
        }

        // --- serial path: value-only max3 tree (depth 4, ~24 instr) ---
        float m1[16];
#pragma unroll
        for (int k = 0; k < 16; ++k)
            m1[k] = fmaxf(fmaxf(s[3 * k], s[3 * k + 1]), s[3 * k + 2]);
        float m2[6];
#pragma unroll
        for (int k = 0; k < 5; ++k)
            m2[k] = fmaxf(fmaxf(m1[3 * k], m1[3 * k + 1]), m1[3 * k + 2]);
        m2[5] = m1[15];
        float best = fmaxf(fmaxf(fmaxf(m2[0], m2[1]), m2[2]),
                           fmaxf(fmaxf(m2[3], m2[4]), m2[5]));

        v = best + e1;                            // serial chain continues here

        // --- off-path: first i with s[i]==best (exact: best is one of s) ---
        int i0 = 63, i1 = 63, i2 = 63, i3 = 63;
#pragma unroll
        for (int k = 11; k >= 0; --k) {           // descending => lowest k wins
            if (s[k]      == best) i0 = k;
            if (s[12 + k] == best) i1 = 12 + k;
            if (s[24 + k] == best) i2 = 24 + k;
            if (s[36 + k] == best) i3 = 36 + k;
        }
        int arg = min(min(i0, i1), min(i2, i3));  // first-max tie-break

        bp[(t - 1) * LL + jc] = (unsigned char)arg;

        e1 = e2; e2 = e3;                         // renamed away by unroll
    }

    // ---- epilogue: final tag (readlanes OK here, runs once) ----
    v += end_tr[jc];
    float sf[LL];
#pragma unroll
    for (int i = 0; i < LL; ++i)
        sf[i] = readlane_f(v, i);
    float bestv; int tag;
    argmax48(sf, bestv, tag);                     // tag is wave-uniform

    int* ob = out + (size_t)b * TT;
    if (j == 0) ob[TT - 1] = tag;

    // ---- backtrack: 32 coalesced row loads + readlane chain + 1 store/chunk ----
    for (int hi = TT - 2; hi >= 0; hi -= 32) {
        int lo = hi - 31; if (lo < 0) lo = 0;
        int n = hi - lo + 1;

        unsigned int row[32];
#pragma unroll
        for (int k = 0; k < 32; ++k)
            row[k] = (unsigned int)bp[(lo + k) * LL + jc];

        int outv = 0;
#pragma unroll
        for (int k = 31; k >= 0; --k) {
            if (k < n) {
                tag = __builtin_amdgcn_readlane((int)row[k], tag);
                outv = (j == k) ? tag : outv;     // tag is SGPR -> one cndmask
            }
        }
        if (j < n) ob[lo + j] = outv;
    }
}

extern "C" void kernel_launch(void* const* d_in, const int* in_sizes, int n_in,
                              void* d_out, int out_size, void* d_ws, size_t ws_size,
                              hipStream_t stream) {
    const float* emissions   = (const float*)d_in[0];
    // d_in[1] = mask — unused by the reference decode body
    const float* transitions = (const float*)d_in[2];
    const float* start_tr    = (const float*)d_in[3];
    const float* end_tr      = (const float*)d_in[4];
    int* out = (int*)d_out;

    viterbi_kernel<<<dim3(BB), dim3(64), 0, stream>>>(
        emissions, transitions, start_tr, end_tr, out);
}

// Round 10
// 573.494 us; speedup vs baseline: 1.6739x; 1.0956x over previous
//
#include <hip/hip_runtime.h>
#include <math.h>

#define BB 512
#define TT 1024
#define LL 48
#define PF 8           // emission prefetch depth (loads in flight)

__device__ __forceinline__ float readlane_f(float v, int lane) {
    return __int_as_float(__builtin_amdgcn_readlane(__float_as_int(v), lane));
}

// Tournament argmax over s[0..47], first-max tie-break (epilogue only).
__device__ __forceinline__ void argmax48(const float* s, float& bestv, int& besti) {
    float val[24];
    int   idx[24];
#pragma unroll
    for (int k = 0; k < 24; ++k) {
        bool c = s[2 * k + 1] > s[2 * k];
        val[k] = c ? s[2 * k + 1] : s[2 * k];
        idx[k] = c ? 2 * k + 1 : 2 * k;
    }
#pragma unroll
    for (int k = 0; k < 12; ++k) {
        bool c = val[2 * k + 1] > val[2 * k];
        val[k] = c ? val[2 * k + 1] : val[2 * k];
        idx[k] = c ? idx[2 * k + 1] : idx[2 * k];
    }
#pragma unroll
    for (int k = 0; k < 6; ++k) {
        bool c = val[2 * k + 1] > val[2 * k];
        val[k] = c ? val[2 * k + 1] : val[2 * k];
        idx[k] = c ? idx[2 * k + 1] : idx[2 * k];
    }
#pragma unroll
    for (int k = 0; k < 3; ++k) {
        bool c = val[2 * k + 1] > val[2 * k];
        val[k] = c ? val[2 * k + 1] : val[2 * k];
        idx[k] = c ? idx[2 * k + 1] : idx[2 * k];
    }
    bool c01 = val[1] > val[0];
    float bv = c01 ? val[1] : val[0];
    int   bi = c01 ? idx[1] : idx[0];
    bool c2 = val[2] > bv;
    bestv = c2 ? val[2] : bv;
    besti = c2 ? idx[2] : bi;
}

__global__ __launch_bounds__(64) void viterbi_kernel(
    const float* __restrict__ emissions,   // [B,T,L]
    const float* __restrict__ transitions, // [L,L]
    const float* __restrict__ start_tr,    // [L]
    const float* __restrict__ end_tr,      // [L]
    int* __restrict__ out)                 // [B,T] int32
{
    __shared__ unsigned char bp[(TT - 1) * LL];   // 49,104 B backpointers

    const int b  = blockIdx.x;
    const int j  = threadIdx.x;
    const int jc = (j < LL) ? j : (LL - 1);       // lanes 48-63 mirror lane 47

    // Transition column jc in registers: tc[i] = transitions[i][jc]
    float tc[LL];
#pragma unroll
    for (int i = 0; i < LL; ++i)
        tc[i] = transitions[i * LL + jc];

    const float* em = emissions + (size_t)b * TT * LL;

    float v = start_tr[jc] + em[jc];

    // 8-deep emission prefetch ring: er[k] holds em[tb + k]; refilled with t+8.
    float er[PF];
#pragma unroll
    for (int k = 0; k < PF; ++k)
        er[k] = em[(size_t)(1 + k) * LL + jc];

    // One Viterbi step at time t consuming emission e (serial chain: v -> v).
    auto step = [&](int t, float e) {
        // broadcast v via readlane, score adds (independent per i)
        float s[LL];
#pragma unroll
        for (int i = 0; i < LL; ++i)
            s[i] = readlane_f(v, i) + tc[i];

        // serial path: value-only max3 tree (depth 4, ~24 instr)
        float m1[16];
#pragma unroll
        for (int k = 0; k < 16; ++k)
            m1[k] = fmaxf(fmaxf(s[3 * k], s[3 * k + 1]), s[3 * k + 2]);
        float m2[6];
#pragma unroll
        for (int k = 0; k < 5; ++k)
            m2[k] = fmaxf(fmaxf(m1[3 * k], m1[3 * k + 1]), m1[3 * k + 2]);
        m2[5] = m1[15];
        float best = fmaxf(fmaxf(fmaxf(m2[0], m2[1]), m2[2]),
                           fmaxf(fmaxf(m2[3], m2[4]), m2[5]));

        v = best + e;                             // chain continues here

        // off-chain: first i with s[i]==best (exact: best is bitwise one of s)
        int i0 = 63, i1 = 63, i2 = 63, i3 = 63;
#pragma unroll
        for (int k = 11; k >= 0; --k) {           // descending => lowest k wins
            if (s[k]      == best) i0 = k;
            if (s[12 + k] == best) i1 = 12 + k;
            if (s[24 + k] == best) i2 = 24 + k;
            if (s[36 + k] == best) i3 = 36 + k;
        }
        int arg = min(min(i0, i1), min(i2, i3));  // first-max tie-break

        bp[(t - 1) * LL + jc] = (unsigned char)arg;
    };

    // Main loop: blocks of 8 with compile-time-constant ring indices.
    int tb = 1;
    for (; tb + PF <= TT; tb += PF) {
#pragma unroll
        for (int k = 0; k < PF; ++k) {
            int t = tb + k;
            float e = er[k];
            int tn = t + PF; if (tn > TT - 1) tn = TT - 1;   // scalar clamp
            er[k] = em[(size_t)tn * LL + jc];     // refill: 8 loads in flight
            step(t, e);
        }
    }
    // Tail: remaining steps, emissions already resident in er[].
#pragma unroll
    for (int k = 0; k < PF - 1; ++k) {
        int t = tb + k;
        if (t < TT) step(t, er[k]);
    }

    // ---- epilogue: final tag (runs once; tournament keeps exact tie-break) ----
    v += end_tr[jc];
    float sf[LL];
#pragma unroll
    for (int i = 0; i < LL; ++i)
        sf[i] = readlane_f(v, i);
    float bestv; int tag;
    argmax48(sf, bestv, tag);                     // tag is wave-uniform

    int* ob = out + (size_t)b * TT;
    if (j == 0) ob[TT - 1] = tag;

    // ---- backtrack: 32 coalesced row loads + readlane chain + 1 store/chunk ----
    for (int hi = TT - 2; hi >= 0; hi -= 32) {
        int lo = hi - 31; if (lo < 0) lo = 0;
        int n = hi - lo + 1;

        unsigned int row[32];
#pragma unroll
        for (int k = 0; k < 32; ++k)
            row[k] = (unsigned int)bp[(lo + k) * LL + jc];

        int outv = 0;
#pragma unroll
        for (int k = 31; k >= 0; --k) {
            if (k < n) {
                tag = __builtin_amdgcn_readlane((int)row[k], tag);
                outv = (j == k) ? tag : outv;     // tag is SGPR -> one cndmask
            }
        }
        if (j < n) ob[lo + j] = outv;
    }
}

extern "C" void kernel_launch(void* const* d_in, const int* in_sizes, int n_in,
                              void* d_out, int out_size, void* d_ws, size_t ws_size,
                              hipStream_t stream) {
    const float* emissions   = (const float*)d_in[0];
    // d_in[1] = mask — unused by the reference decode body
    const float* transitions = (const float*)d_in[2];
    const float* start_tr    = (const float*)d_in[3];
    const float* end_tr      = (const float*)d_in[4];
    int* out = (int*)d_out;

    viterbi_kernel<<<dim3(BB), dim3(64), 0, stream>>>(
        emissions, transitions, start_tr, end_tr, out);
}